// Round 3
// baseline (235.700 us; speedup 1.0000x reference)
//
#include <hip/hip_runtime.h>

#define LOG2E 1.4426950408889634f

typedef float v2f __attribute__((ext_vector_type(2)));

__device__ __forceinline__ float bcastf(float v, int lane) {
    return __uint_as_float(__builtin_amdgcn_readlane(__float_as_uint(v), lane));
}

// Quad broadcast via DPP quad_perm (0x00/0x55/0xAA/0xFF = bcast lane 0/1/2/3 of quad)
template<int CTRL>
__device__ __forceinline__ float qb(float v) {
    return __uint_as_float(__builtin_amdgcn_update_dpp(
        0, __float_as_uint(v), CTRL, 0xF, 0xF, true));
}

// sigmoid / scaled-tanh from pre-scaled gate input p
__device__ __forceinline__ float gate_act(float p, float aa, float ac) {
    const float e = __builtin_amdgcn_exp2f(p);
    return fmaf(aa, __builtin_amdgcn_rcpf(1.0f + e), ac);
}

// Quad gather i/f/g/o + cell update in exp2-domain (cs = -2log2e * c).
__device__ __forceinline__ void cell_update(float act, float& cs, float& h) {
    const float iv = qb<0x00>(act);
    const float fv = qb<0x55>(act);
    const float gv = qb<0xAA>(act);   // = K * tanh(gate_g)
    const float ov = qb<0xFF>(act);
    cs = fmaf(fv, cs, iv * gv);
    const float e  = __builtin_amdgcn_exp2f(cs);
    const float th = fmaf(2.0f, __builtin_amdgcn_rcpf(1.0f + e), -1.0f);
    h = ov * th;
}

// ---------------------------------------------------------------------------
// One block, 512 threads. Phase 1: wave 0 = LSTM layer 1, wave 1 = LSTM
// layer 2 (lagging 2 steps), handshake via LDS ring buffer + one
// __syncthreads per step. Waves 2-7 just spin on the barriers.
// Lane layout within each wave: lane = 4*cell + gate (i=0,f=1,g=2,o=3);
// original weight row = gate*16 + cell. Weights pre-scaled by -log2e
// (i,f,o) / -2log2e (g) so exp2 consumes raw FMA output.
// Phase 2: all 512 threads, per-timestep MLP 16->64->32->1.
// ---------------------------------------------------------------------------
__global__ __launch_bounds__(512, 1) void lstm_fused_kernel(
    const float* __restrict__ x,
    const float* __restrict__ Wih0, const float* __restrict__ Whh0,
    const float* __restrict__ bih0, const float* __restrict__ bhh0,
    const float* __restrict__ Wih1, const float* __restrict__ Whh1,
    const float* __restrict__ bih1, const float* __restrict__ bhh1,
    const float* __restrict__ W1, const float* __restrict__ b1,
    const float* __restrict__ W2, const float* __restrict__ b2,
    const float* __restrict__ W3, const float* __restrict__ b3,
    float* __restrict__ out)
{
    const int tid = threadIdx.x;
    const int wid = tid >> 6;
    const int j   = tid & 63;
    const int m   = j >> 2;
    const int g   = j & 3;
    const int row = g * 16 + m;

    __shared__ __align__(16) float xs[516];
    __shared__ __align__(16) float h1buf[4][16];
    __shared__ __align__(16) float h2s[512 * 16];

    // Stage x[t, 4095, 0] (one uncoalesced gather, all waves help).
    xs[tid] = x[tid * 4096 + 4095];
    if (tid < 4) xs[512 + tid] = 0.0f;

    const float K  = -2.0f * LOG2E;
    const float sc = (g == 2) ? K : -LOG2E;
    const float aa = (g == 2) ? (2.0f * K) : 1.0f;
    const float ac = (g == 2) ? (-K)       : 0.0f;

    // Per-wave weight setup.
    float whh0[16]; float wx0 = 0.f, bias0 = 0.f;
    v2f   wih1p[8]; float whh1[16]; float bias1 = 0.f;

    if (wid == 0) {
        #pragma unroll
        for (int k = 0; k < 16; ++k) whh0[k] = Whh0[row * 16 + k] * sc;
        wx0   = Wih0[row] * sc;
        bias0 = (bih0[row] + bhh0[row]) * sc;
    } else if (wid == 1) {
        #pragma unroll
        for (int k = 0; k < 8; ++k)
            wih1p[k] = (v2f){Wih1[row * 16 + 2 * k] * sc,
                             Wih1[row * 16 + 2 * k + 1] * sc};
        #pragma unroll
        for (int k = 0; k < 16; ++k) whh1[k] = Whh1[row * 16 + k] * sc;
        bias1 = (bih1[row] + bhh1[row]) * sc;
    }
    __syncthreads();

    float h1 = 0.f, c1s = 0.f, h2 = 0.f, c2s = 0.f;
    float xcur = xs[0];
    float4 bufA[4], bufB[4];   // wave-1 ping-pong copies of h1

    // Layer-1 step i (wave 0).  Chain: h1 -> readlane -> dot -> act -> cell.
    auto l1_step = [&](int i) {
        if (i < 512) {
            const float xnext = xs[i + 1];          // prefetch (pad at 512)
            float s1[16];
            #pragma unroll
            for (int k = 0; k < 16; ++k) s1[k] = bcastf(h1, 4 * k);
            float a0 = fmaf(whh0[0], s1[0], bias0);
            float a1 = whh0[1] * s1[1];
            float a2 = whh0[2] * s1[2];
            float a3 = whh0[3] * s1[3];
            #pragma unroll
            for (int k = 4; k < 16; k += 4) {
                a0 = fmaf(whh0[k + 0], s1[k + 0], a0);
                a1 = fmaf(whh0[k + 1], s1[k + 1], a1);
                a2 = fmaf(whh0[k + 2], s1[k + 2], a2);
                a3 = fmaf(whh0[k + 3], s1[k + 3], a3);
            }
            float p1 = (a0 + a1) + (a2 + a3);
            p1 = fmaf(wx0, xcur, p1);
            cell_update(gate_act(p1, aa, ac), c1s, h1);
            if (g == 0) h1buf[i & 3][m] = h1;
            xcur = xnext;
        }
    };

    // Layer-2 at iteration i computes step i-2 from cur (= h1(i-2)) and
    // prefetches h1(i-1) into nxt.
    auto l2_step = [&](int i, float4* cur, float4* nxt) {
        if (i >= 1) {   // prefetch h1(i-1) (written end of iter i-1, barrier-ordered)
            const float4* p = reinterpret_cast<const float4*>(h1buf[(i - 1) & 3]);
            nxt[0] = p[0]; nxt[1] = p[1]; nxt[2] = p[2]; nxt[3] = p[3];
        }
        if (i >= 2) {
            float s2[16];
            #pragma unroll
            for (int k = 0; k < 16; ++k) s2[k] = bcastf(h2, 4 * k);

            // Wih1 . h1(i-2) with packed FMAs (VGPR pairs from float4 loads).
            v2f q0 = (v2f){cur[0].x, cur[0].y}, q1 = (v2f){cur[0].z, cur[0].w};
            v2f q2 = (v2f){cur[1].x, cur[1].y}, q3 = (v2f){cur[1].z, cur[1].w};
            v2f q4 = (v2f){cur[2].x, cur[2].y}, q5 = (v2f){cur[2].z, cur[2].w};
            v2f q6 = (v2f){cur[3].x, cur[3].y}, q7 = (v2f){cur[3].z, cur[3].w};
            v2f pk0 = wih1p[0] * q0;
            v2f pk1 = wih1p[1] * q1;
            pk0 = __builtin_elementwise_fma(wih1p[2], q2, pk0);
            pk1 = __builtin_elementwise_fma(wih1p[3], q3, pk1);
            pk0 = __builtin_elementwise_fma(wih1p[4], q4, pk0);
            pk1 = __builtin_elementwise_fma(wih1p[5], q5, pk1);
            pk0 = __builtin_elementwise_fma(wih1p[6], q6, pk0);
            pk1 = __builtin_elementwise_fma(wih1p[7], q7, pk1);

            // Whh1 . h2(i-3) scalar (SGPR operands from readlanes).
            float a0 = fmaf(whh1[0], s2[0], bias1);
            float a1 = whh1[1] * s2[1];
            float a2 = whh1[2] * s2[2];
            float a3 = whh1[3] * s2[3];
            #pragma unroll
            for (int k = 4; k < 16; k += 4) {
                a0 = fmaf(whh1[k + 0], s2[k + 0], a0);
                a1 = fmaf(whh1[k + 1], s2[k + 1], a1);
                a2 = fmaf(whh1[k + 2], s2[k + 2], a2);
                a3 = fmaf(whh1[k + 3], s2[k + 3], a3);
            }
            const v2f pks = pk0 + pk1;
            const float p2 = ((a0 + a1) + (a2 + a3)) + (pks.x + pks.y);
            cell_update(gate_act(p2, aa, ac), c2s, h2);
            if (g == 0) h2s[(i - 2) * 16 + m] = h2;
        }
    };

    // 514 iterations (layer 2 lags by 2), unrolled by 2 for buffer ping-pong.
    for (int i2 = 0; i2 < 514; i2 += 2) {
        __syncthreads();
        if (wid == 0)      l1_step(i2);
        else if (wid == 1) l2_step(i2, bufA, bufB);
        __syncthreads();
        if (wid == 0)      l1_step(i2 + 1);
        else if (wid == 1) l2_step(i2 + 1, bufB, bufA);
    }
    __syncthreads();

    // ---- Phase 2: MLP 16 -> 64 -> 32 -> 1, one timestep row per thread ----
    const int r = tid;

    float h[16];
    #pragma unroll
    for (int q = 0; q < 4; ++q) {
        const float4 v = reinterpret_cast<const float4*>(&h2s[r * 16])[q];
        h[4 * q + 0] = v.x; h[4 * q + 1] = v.y;
        h[4 * q + 2] = v.z; h[4 * q + 3] = v.w;
    }

    float a1[64];
    #pragma unroll
    for (int u = 0; u < 64; ++u) {
        const float4* wr = reinterpret_cast<const float4*>(W1 + u * 16);
        float s = b1[u];
        #pragma unroll
        for (int q = 0; q < 4; ++q) {
            const float4 w = wr[q];
            s = fmaf(w.x, h[4 * q + 0], s);
            s = fmaf(w.y, h[4 * q + 1], s);
            s = fmaf(w.z, h[4 * q + 2], s);
            s = fmaf(w.w, h[4 * q + 3], s);
        }
        a1[u] = fmaxf(s, 0.0f);
    }

    float o = b3[0];
    #pragma unroll
    for (int v = 0; v < 32; ++v) {
        const float4* wr = reinterpret_cast<const float4*>(W2 + v * 64);
        float s = b2[v];
        #pragma unroll
        for (int q = 0; q < 16; ++q) {
            const float4 w = wr[q];
            s = fmaf(w.x, a1[4 * q + 0], s);
            s = fmaf(w.y, a1[4 * q + 1], s);
            s = fmaf(w.z, a1[4 * q + 2], s);
            s = fmaf(w.w, a1[4 * q + 3], s);
        }
        o = fmaf(fmaxf(s, 0.0f), W3[v], o);
    }
    out[r] = o;
}

extern "C" void kernel_launch(void* const* d_in, const int* in_sizes, int n_in,
                              void* d_out, int out_size, void* d_ws, size_t ws_size,
                              hipStream_t stream) {
    const float* x    = (const float*)d_in[0];
    const float* Wih0 = (const float*)d_in[1];
    const float* Whh0 = (const float*)d_in[2];
    const float* bih0 = (const float*)d_in[3];
    const float* bhh0 = (const float*)d_in[4];
    const float* Wih1 = (const float*)d_in[5];
    const float* Whh1 = (const float*)d_in[6];
    const float* bih1 = (const float*)d_in[7];
    const float* bhh1 = (const float*)d_in[8];
    const float* W1   = (const float*)d_in[9];
    const float* b1   = (const float*)d_in[10];
    const float* W2   = (const float*)d_in[11];
    const float* b2   = (const float*)d_in[12];
    const float* W3   = (const float*)d_in[13];
    const float* b3   = (const float*)d_in[14];

    hipLaunchKernelGGL(lstm_fused_kernel, dim3(1), dim3(512), 0, stream,
                       x, Wih0, Whh0, bih0, bhh0, Wih1, Whh1, bih1, bhh1,
                       W1, b1, W2, b2, W3, b3, (float*)d_out);
}